// Round 3
// baseline (629.621 us; speedup 1.0000x reference)
//
#include <hip/hip_runtime.h>
#include <cmath>

#define B_   2
#define S_   2048
#define H_   2304
#define NH_  8
#define HD_  256
#define NKV_ 4
#define WIN_ 512
#define QKVW 4096   // fused QKV output row width (8+4+4 heads * 256)

typedef unsigned short ushort_t;
typedef __attribute__((ext_vector_type(8))) short bf16x8;     // 8 bf16 = 4 VGPRs
typedef __attribute__((ext_vector_type(4))) float floatx4;

// round-to-nearest-even fp32 -> bf16
__device__ __forceinline__ unsigned short f2bf(float f) {
  unsigned u = __builtin_bit_cast(unsigned, f);
  u += 0x7fff + ((u >> 16) & 1);
  return (unsigned short)(u >> 16);
}
__device__ __forceinline__ float bf2f(ushort_t v) {
  unsigned u = (unsigned)v << 16;
  return __builtin_bit_cast(float, u);
}

// async global->LDS, 16 B per lane. LDS dest = wave-uniform base + lane*16.
__device__ __forceinline__ void gl2lds16(const void* g, void* l) {
  __builtin_amdgcn_global_load_lds(
      (const __attribute__((address_space(1))) unsigned int*)g,
      (__attribute__((address_space(3))) unsigned int*)l, 16, 0, 0);
}

// ---------------------------------------------------------------------------
// Elementwise fp32 -> bf16 cast (4 elems/thread).
// ---------------------------------------------------------------------------
__global__ void cast_bf16(const float* __restrict__ in, ushort_t* __restrict__ out) {
  const int i = blockIdx.x * 256 + threadIdx.x;
  float4 v = ((const float4*)in)[i];
  ushort4 o;
  o.x = f2bf(v.x); o.y = f2bf(v.y); o.z = f2bf(v.z); o.w = f2bf(v.w);
  ((ushort4*)out)[i] = o;
}

// ---------------------------------------------------------------------------
// W[K,N] fp32 -> Wt[N,K] bf16 (32x32 LDS tiles, 256 threads).
// ---------------------------------------------------------------------------
__global__ void transpose_cast(const float* __restrict__ W, ushort_t* __restrict__ Wt,
                               int K, int N) {
  __shared__ float t[32][33];
  const int lx = threadIdx.x & 31, ly = threadIdx.x >> 5;   // ly 0..7
  const int n0 = blockIdx.x * 32, k0 = blockIdx.y * 32;
#pragma unroll
  for (int i = 0; i < 4; ++i)
    t[ly + i * 8][lx] = W[(long long)(k0 + ly + i * 8) * N + n0 + lx];
  __syncthreads();
#pragma unroll
  for (int i = 0; i < 4; ++i)
    Wt[(long long)(n0 + ly + i * 8) * K + k0 + lx] = f2bf(t[lx][ly + i * 8]);
}

// ===========================================================================
// 256x256-tile pipelined bf16 MFMA GEMM:  C[M,N] = A[M,K] @ Bt[N,K]^T
// 512 threads = 8 waves (2M x 4N), per-wave 128x64 (acc[8][4]), BK=64,
// 128 KiB dynamic LDS double buffer, global_load_lds width=16 with
// chunk^(row&7) swizzle via pre-swizzled GLOBAL source (linear LDS dest).
//
// v3 (overlap fix): 2-K-tile unrolled loop, 8 phases. ds_reads for phase
// p+1 are issued at the START of phase p into a DISJOINT register set
// (aA/aB, bA/bB), so the LDS pipe drains them under phase p's 16-MFMA
// cluster. No explicit lgkm drains: the compiler's auto-waitcnt emits
// minimal counted waits before each consuming MFMA. Quadrant order per
// tile parity (even: q00,q01,q11,q10; odd: q01,q00,q10,q11) makes every
// read target a set whose last use was >=1 phase earlier.
//
// Reads:   P1: bB<-B1(t), aB<-A1(t)        P4: aA<-A0(t+1), bB<-B1(t+1)
//          P5: bA<-B0(t+1), aB<-A1(t+1)    P8: aA<-A0(t+2), bA<-B0(t+2)
// MFMA:    P1 q00(t):aA,bA   P2 q01(t):aA,bB   P3 q11(t):aB,bB
//          P4 q10(t):aB,bA   P5 q01(t+1):aA,bB P6 q00(t+1):aA,bA
//          P7 q10(t+1):aB,bA P8 q11(t+1):aB,bB
// Stages:  P1 A1(t+1); P2 A0(t+2); P3 B0(t+2); P4 B1(t+2);
//          P5 A1(t+2); P6 A0(t+3); P7 B0(t+3); P8 B1(t+3)
// vmcnt(4) at P3/P7-end drains exactly tile t+1 / t+2 (12 outstanding ->
// keep newest 4 = {A0,B0} of the tile after next); vmcnt(0) on last pair.
// WAR safety checked per region: readers wait-complete >=1 barrier before
// the region's re-stage issues.
// ===========================================================================
#define LDA_SET(dst_, base_, qm_) do { \
  _Pragma("unroll") for (int i_ = 0; i_ < 4; ++i_) { \
    const int row_ = wm + (qm_) * 64 + i_ * 16 + l15; \
    _Pragma("unroll") for (int kk_ = 0; kk_ < 2; ++kk_) \
      dst_[i_][kk_] = *(const bf16x8*)&(base_)[row_ * 64 + (((kk_ * 4 + lq) ^ (l15 & 7)) * 8)]; \
  } \
} while (0)

#define LDB_SET(dst_, base_, qn_) do { \
  _Pragma("unroll") for (int j_ = 0; j_ < 2; ++j_) { \
    const int row_ = wn + (qn_) * 32 + j_ * 16 + l15; \
    _Pragma("unroll") for (int kk_ = 0; kk_ < 2; ++kk_) \
      dst_[j_][kk_] = *(const bf16x8*)&(base_)[row_ * 64 + (((kk_ * 4 + lq) ^ (l15 & 7)) * 8)]; \
  } \
} while (0)

#define MFMA_Q(qm_, qn_, aset_, bset_) do { \
  __builtin_amdgcn_s_setprio(1); \
  _Pragma("unroll") for (int kk_ = 0; kk_ < 2; ++kk_) \
  _Pragma("unroll") for (int i_ = 0; i_ < 4; ++i_) \
  _Pragma("unroll") for (int j_ = 0; j_ < 2; ++j_) \
    acc[(qm_) * 4 + i_][(qn_) * 2 + j_] = __builtin_amdgcn_mfma_f32_16x16x32_bf16( \
        aset_[i_][kk_], bset_[j_][kk_], acc[(qm_) * 4 + i_][(qn_) * 2 + j_], 0, 0, 0); \
  __builtin_amdgcn_s_setprio(0); \
} while (0)

// stage one 128-row x 64-col half-tile (16 KB): 2 x global_load_lds per lane.
#define STAGE_A(dst_, gsrc_, t_, qm_) do { \
  _Pragma("unroll") for (int jj_ = 0; jj_ < 2; ++jj_) { \
    const int g_ = w * 2 + jj_; \
    const int tr0_ = ((g_ >> 3) * 128) + (qm_) * 64 + (g_ & 7) * 8; \
    gl2lds16(gsrc_ + (size_t)tr0_ * K + (size_t)(t_) * 64 + laneOff, dst_ + tr0_ * 64); \
  } \
} while (0)

#define STAGE_B(dst_, gsrc_, t_, qn_) do { \
  _Pragma("unroll") for (int jj_ = 0; jj_ < 2; ++jj_) { \
    const int g_ = w * 2 + jj_; \
    const int tr0_ = ((g_ >> 2) * 64) + (qn_) * 32 + (g_ & 3) * 8; \
    gl2lds16(gsrc_ + (size_t)tr0_ * K + (size_t)(t_) * 64 + laneOff, dst_ + tr0_ * 64); \
  } \
} while (0)

#define BAR()  asm volatile("s_barrier" ::: "memory")
#define VM(n_) asm volatile("s_waitcnt vmcnt(" #n_ ")" ::: "memory")

template <bool OUT_BF16>
__launch_bounds__(512)
__global__ void gemm_8ph(const ushort_t* __restrict__ A,   // [M,K] bf16
                         const ushort_t* __restrict__ Bt,  // [N,K] bf16
                         void* __restrict__ Cv, int M, int N, int K) {
  extern __shared__ __attribute__((aligned(128))) ushort_t smem[];
  const int tid = threadIdx.x, lane = tid & 63, w = tid >> 6;   // w 0..7
  const int wm = (w >> 2) * 128, wn = (w & 3) * 64;
  const int l15 = lane & 15, lq = lane >> 4;

  // T1: XCD-aware swizzle of the linear block id (grid %8 == 0 for both GEMMs)
  const int nwg  = gridDim.x * gridDim.y;
  const int orig = blockIdx.y * gridDim.x + blockIdx.x;
  const int cpx  = nwg >> 3;
  const int swz  = (orig & 7) * cpx + (orig >> 3);
  const int bx   = swz % gridDim.x, by = swz / gridDim.x;
  const int bm = by * 256, bn = bx * 256;
  const int NT = K >> 6;   // even for both GEMMs (36, 32)

  const ushort_t* Ab = A + (size_t)bm * K;
  const ushort_t* Bb = Bt + (size_t)bn * K;
  // per-lane source offset: row += lane>>3, chunk = (lane&7)^(lane>>3) (swizzle)
  const size_t laneOff = (size_t)(lane >> 3) * K + (size_t)(((lane & 7) ^ (lane >> 3)) * 8);

  // LDS layout: A-even, A-odd, B-even, B-odd (A imms < 64K, B imms from B-base)
  ushort_t* Ae = smem;              // even-tile A (256x64)
  ushort_t* Ao = smem + 16384;      // odd-tile  A
  ushort_t* Be = smem + 32768;      // even-tile B
  ushort_t* Bo = smem + 49152;      // odd-tile  B

  floatx4 acc[8][4] = {};
  bf16x8 aA[4][2], aB[4][2], bA[2][2], bB[2][2];

  // ---- prologue: tile0 fully + tile1's {A0,B0,B1} (issue order matters for vmcnt)
  STAGE_A(Ae, Ab, 0, 0);
  STAGE_B(Be, Bb, 0, 0);
  STAGE_B(Be, Bb, 0, 1);
  STAGE_A(Ae, Ab, 0, 1);
  if (NT > 1) {
    STAGE_A(Ao, Ab, 1, 0);
    STAGE_B(Bo, Bb, 1, 0);
    STAGE_B(Bo, Bb, 1, 1);
    VM(6);                        // tile0 landed; tile1 pieces in flight
  } else {
    VM(0);
  }
  BAR();
  LDA_SET(aA, Ae, 0);             // A0(0)
  LDB_SET(bA, Be, 0);             // B0(0)

  for (int t = 0; t < NT; t += 2) {
    // ---- P1: q00(t)=aA,bA | reads bB<-B1(t), aB<-A1(t) | stage A1(t+1)
    LDB_SET(bB, Be, 1);
    LDA_SET(aB, Ae, 1);
    STAGE_A(Ao, Ab, t + 1, 1);
    MFMA_Q(0, 0, aA, bA);
    BAR();

    // ---- P2: q01(t)=aA,bB | stage A0(t+2)
    if (t + 2 < NT) STAGE_A(Ae, Ab, t + 2, 0);
    MFMA_Q(0, 1, aA, bB);
    BAR();

    // ---- P3: q11(t)=aB,bB | stage B0(t+2) | vmcnt: tile t+1 fully landed
    if (t + 2 < NT) STAGE_B(Be, Bb, t + 2, 0);
    MFMA_Q(1, 1, aB, bB);
    if (t + 2 < NT) { VM(4); } else { VM(0); }
    BAR();

    // ---- P4: q10(t)=aB,bA | reads aA<-A0(t+1), bB<-B1(t+1) | stage B1(t+2)
    LDA_SET(aA, Ao, 0);
    LDB_SET(bB, Bo, 1);
    if (t + 2 < NT) STAGE_B(Be, Bb, t + 2, 1);
    MFMA_Q(1, 0, aB, bA);
    BAR();

    // ---- P5: q01(t+1)=aA,bB | reads bA<-B0(t+1), aB<-A1(t+1) | stage A1(t+2)
    LDB_SET(bA, Bo, 0);
    LDA_SET(aB, Ao, 1);
    if (t + 2 < NT) STAGE_A(Ae, Ab, t + 2, 1);
    MFMA_Q(0, 1, aA, bB);
    BAR();

    // ---- P6: q00(t+1)=aA,bA | stage A0(t+3)
    if (t + 3 < NT) STAGE_A(Ao, Ab, t + 3, 0);
    MFMA_Q(0, 0, aA, bA);
    BAR();

    // ---- P7: q10(t+1)=aB,bA | stage B0(t+3) | vmcnt: tile t+2 fully landed
    if (t + 3 < NT) STAGE_B(Bo, Bb, t + 3, 0);
    MFMA_Q(1, 0, aB, bA);
    if (t + 2 < NT) { VM(4); }
    BAR();

    // ---- P8: q11(t+1)=aB,bB | reads aA<-A0(t+2), bA<-B0(t+2) | stage B1(t+3)
    if (t + 2 < NT) {
      LDA_SET(aA, Ae, 0);
      LDB_SET(bA, Be, 0);
    }
    if (t + 3 < NT) STAGE_B(Bo, Bb, t + 3, 1);
    MFMA_Q(1, 1, aB, bB);
    BAR();
  }

  // ---- epilogue: C write (C/D layout: row = lq*4+rr, col = l15 per 16x16 frag)
  const int r0 = lq * 4;
#pragma unroll
  for (int mf = 0; mf < 8; ++mf)
#pragma unroll
    for (int nf = 0; nf < 4; ++nf) {
      const long long base = (long long)(bm + wm + mf * 16 + r0) * N + bn + wn + nf * 16 + l15;
      if (OUT_BF16) {
        ushort_t* Cp = (ushort_t*)Cv + base;
#pragma unroll
        for (int rr = 0; rr < 4; ++rr) Cp[(long long)rr * N] = f2bf(acc[mf][nf][rr]);
      } else {
        float* Cp = (float*)Cv + base;
#pragma unroll
        for (int rr = 0; rr < 4; ++rr) Cp[(long long)rr * N] = acc[mf][nf][rr];
      }
    }
}

#undef LDA_SET
#undef LDB_SET
#undef MFMA_Q
#undef STAGE_A
#undef STAGE_B
#undef BAR
#undef VM

// ---------------------------------------------------------------------------
// Fallback 128x128 GEMM (register-double-buffered) — used only if the
// dynamic-LDS attribute is unavailable.
// ---------------------------------------------------------------------------
template <bool OUT_BF16>
__launch_bounds__(256)
__global__ void gemm_bt(const ushort_t* __restrict__ A,   // [M,K] bf16
                        const ushort_t* __restrict__ Bt,  // [N,K] bf16
                        void* __restrict__ Cv, int M, int N, int K) {
  __shared__ ushort_t As[128 * 64];
  __shared__ ushort_t Bs[128 * 64];
  const int tid = threadIdx.x, lane = tid & 63, wid = tid >> 6;
  const int bm = blockIdx.y * 128, bn = blockIdx.x * 128;
  const int wm = (wid >> 1) * 64, wn = (wid & 1) * 64;

  floatx4 acc[4][4] = {};

  const int r  = tid >> 1;
  const int cp = (tid & 1) * 4;
  const int wkey = r & 7;
  const ushort_t* Ap = A  + (long long)(bm + r) * K + cp * 8;
  const ushort_t* Bp = Bt + (long long)(bn + r) * K + cp * 8;
  ushort_t* Aw = &As[r * 64];
  ushort_t* Bw = &Bs[r * 64];

  const int l15 = lane & 15, lq = lane >> 4;
  const int rkey = l15 & 7;

  bf16x8 ar[4], br[4];
#pragma unroll
  for (int i = 0; i < 4; ++i) {
    ar[i] = *(const bf16x8*)(Ap + i * 8);
    br[i] = *(const bf16x8*)(Bp + i * 8);
  }

  for (int k0 = 0; k0 < K; k0 += 64) {
    __syncthreads();
#pragma unroll
    for (int i = 0; i < 4; ++i) {
      *(bf16x8*)&Aw[((cp + i) ^ wkey) * 8] = ar[i];
      *(bf16x8*)&Bw[((cp + i) ^ wkey) * 8] = br[i];
    }
    __syncthreads();

    if (k0 + 64 < K) {
      const int kn = k0 + 64;
#pragma unroll
      for (int i = 0; i < 4; ++i) {
        ar[i] = *(const bf16x8*)(Ap + kn + i * 8);
        br[i] = *(const bf16x8*)(Bp + kn + i * 8);
      }
    }

#pragma unroll
    for (int kk = 0; kk < 2; ++kk) {
      bf16x8 af[4], bfr[4];
#pragma unroll
      for (int i = 0; i < 4; ++i) {
        af[i]  = *(const bf16x8*)&As[(wm + i * 16 + l15) * 64 + ((kk * 4 + lq) ^ rkey) * 8];
        bfr[i] = *(const bf16x8*)&Bs[(wn + i * 16 + l15) * 64 + ((kk * 4 + lq) ^ rkey) * 8];
      }
#pragma unroll
      for (int i = 0; i < 4; ++i)
#pragma unroll
        for (int j = 0; j < 4; ++j)
          acc[i][j] = __builtin_amdgcn_mfma_f32_16x16x32_bf16(af[i], bfr[j], acc[i][j], 0, 0, 0);
    }
  }

  const int r0 = lq * 4, c0 = l15;
#pragma unroll
  for (int i = 0; i < 4; ++i)
#pragma unroll
    for (int j = 0; j < 4; ++j) {
      const long long base = (long long)(bm + wm + i * 16 + r0) * N + bn + wn + j * 16 + c0;
      if (OUT_BF16) {
        ushort_t* Cp = (ushort_t*)Cv + base;
#pragma unroll
        for (int rr = 0; rr < 4; ++rr) Cp[(long long)rr * N] = f2bf(acc[i][j][rr]);
      } else {
        float* Cp = (float*)Cv + base;
#pragma unroll
        for (int rr = 0; rr < 4; ++rr) Cp[(long long)rr * N] = acc[i][j][rr];
      }
    }
}

// ---------------------------------------------------------------------------
// In-place RoPE on QKV16 [B*S][4096] bf16 (Q cols 0..2047, K cols 2048..3071).
// Also folds the 1/16 attention scale into Q. V region untouched.
// ---------------------------------------------------------------------------
__global__ void rope_inplace(ushort_t* __restrict__ QKV16, const int* __restrict__ pos) {
  const int bs  = blockIdx.x;
  const int gid = blockIdx.y * 256 + threadIdx.x;
  const int head = gid >> 7;          // 0..11
  const int d    = gid & 127;
  const float pp   = (float)pos[bs];
  const float invf = __expf(-(float)d * (9.210340371976184f / 128.0f));
  const float ang  = pp * invf;
  float sn, cc;
  __sincosf(ang, &sn, &cc);
  ushort_t* base = QKV16 + (size_t)bs * QKVW + head * HD_;
  const float x1 = bf2f(base[d]);
  const float x2 = bf2f(base[d + 128]);
  float o1 = x1 * cc - x2 * sn;
  float o2 = x2 * cc + x1 * sn;
  if (head < NH_) { o1 *= 0.0625f; o2 *= 0.0625f; }   // fold 1/sqrt(256) into Q
  base[d]       = f2bf(o1);
  base[d + 128] = f2bf(o2);
}

// ---------------------------------------------------------------------------
// V transpose: QKV16 V region -> Vt16 [B][NKV][256][S] bf16.
// ---------------------------------------------------------------------------
__global__ void v_prep(const ushort_t* __restrict__ QKV16, ushort_t* __restrict__ Vt16) {
  __shared__ ushort_t tile[32][33];
  const int k0 = blockIdx.x * 32, d0 = blockIdx.y * 32;
  const int b = blockIdx.z >> 2, hk = blockIdx.z & 3;
  const int lx = threadIdx.x & 31, ly = threadIdx.x >> 5;
#pragma unroll
  for (int i = 0; i < 4; ++i)
    tile[ly + 8 * i][lx] =
        QKV16[(size_t)(b * S_ + k0 + ly + 8 * i) * QKVW + 3072 + hk * HD_ + d0 + lx];
  __syncthreads();
#pragma unroll
  for (int i = 0; i < 4; ++i)
    Vt16[((size_t)(b * NKV_ + hk) * HD_ + d0 + ly + 8 * i) * S_ + k0 + lx] =
        tile[lx][ly + 8 * i];
}

// ---------------------------------------------------------------------------
// MFMA flash attention, head-PAIR per block (both heads share hk's K/V).
// 512 threads = 8 waves: waves 0-3 -> head 2*hp, waves 4-7 -> head 2*hp+1.
// ---------------------------------------------------------------------------
__launch_bounds__(512)
__global__ void attn_mfma(const ushort_t* __restrict__ QKV16,  // [B*S][4096]
                          const ushort_t* __restrict__ Vt16,   // [B][NKV][256][S]
                          ushort_t* __restrict__ AOb) {        // [B][S][NH][256]
  __shared__ ushort_t Ks[32 * 256];    // [key][dim], chunk-swizzled
  __shared__ ushort_t Vts[256 * 32];   // [dim][key], chunk-swizzled
  __shared__ ushort_t Ps[8][16 * 32];  // per-wave P [q][key], chunk-swizzled
  __shared__ float rsb[8][16];

  const int lane = threadIdx.x & 63, w = threadIdx.x >> 6;   // w 0..7
  const int l15 = lane & 15, lq = lane >> 4;
  const int qb = blockIdx.x * 64;
  const int hp = blockIdx.y, b = blockIdx.z;                 // hp = hk
  const int h  = hp * 2 + (w >> 2);
  const int hw = w & 3;                                      // wave-in-head

  const ushort_t* Qh = QKV16 + (size_t)b * S_ * QKVW + h * HD_;
  const ushort_t* Kh = QKV16 + (size_t)b * S_ * QKVW + 2048 + hp * HD_;
  const ushort_t* Vh = Vt16 + ((size_t)(b * NKV_ + hp) * HD_) * S_;

  const int qw = qb + hw * 16;   // wave's first query

  bf16x8 afq[8];
  {
    const ushort_t* qr = Qh + (size_t)(qw + l15) * QKVW + lq * 8;
#pragma unroll
    for (int kd = 0; kd < 8; ++kd) afq[kd] = *(const bf16x8*)(qr + kd * 32);
  }

  floatx4 acc[16] = {};
  float rs[4] = {0.f, 0.f, 0.f, 0.f};

  int kb0 = qb - (WIN_ - 1);
  if (kb0 < 0) kb0 = 0;
  kb0 &= ~31;

  const int ksp = lane & 31, ksr = lane >> 5;
  const int vsp = lane & 3,  vsr = lane >> 2;

  for (int kb = kb0; kb < qb + 64; kb += 32) {
    __syncthreads();
#pragma unroll
    for (int i = 0; i < 2; ++i) {
      const int kl = w * 4 + 2 * i + ksr;
      gl2lds16(Kh + (size_t)(kb + kl) * QKVW + (ksp ^ (kl & 31)) * 8,
               &Ks[(w * 4 + 2 * i) * 256]);
    }
#pragma unroll
    for (int i = 0; i < 2; ++i) {
      const int dl = w * 32 + 16 * i + vsr;
      gl2lds16(Vh + (size_t)dl * S_ + kb + (vsp ^ ((dl >> 1) & 3)) * 8,
               &Vts[(w * 32 + 16 * i) * 32]);
    }
    __syncthreads();

    if (kb <= qw + 15 && kb + 31 >= qw - (WIN_ - 1)) {
      ushort_t* Pw = Ps[w];
#pragma unroll
      for (int kt = 0; kt < 2; ++kt) {
        floatx4 sacc = {};
        const int keyl = kt * 16 + l15;
        const int krow = keyl * 256;
        const int ksw = keyl & 31;
#pragma unroll
        for (int kd = 0; kd < 8; ++kd) {
          bf16x8 bk = *(const bf16x8*)&Ks[krow + ((kd * 4 + lq) ^ ksw) * 8];
          sacc = __builtin_amdgcn_mfma_f32_16x16x32_bf16(afq[kd], bk, sacc, 0, 0, 0);
        }
        const int keyg = kb + keyl;
#pragma unroll
        for (int rr = 0; rr < 4; ++rr) {
          const int qg = qw + lq * 4 + rr;
          const float t = __expf(sacc[rr] * 0.04f);
          const float L = 50.f - __fdividef(100.f, t + 1.f);
          float p = __expf(L);
          p = (keyg <= qg && keyg >= qg - (WIN_ - 1)) ? p : 0.f;
          rs[rr] += p;
          const int ql = lq * 4 + rr;
          const int ch = kt * 2 + (l15 >> 3);
          Pw[ql * 32 + ((ch ^ ((ql >> 1) & 3)) * 8) + (l15 & 7)] = f2bf(p);
        }
      }
      asm volatile("s_waitcnt lgkmcnt(0)" ::: "memory");

      const bf16x8 bp = *(const bf16x8*)&Pw[l15 * 32 + ((lq ^ ((l15 >> 1) & 3)) * 8)];
      const int vsw = (l15 >> 1) & 3;
#pragma unroll
      for (int t = 0; t < 16; ++t) {
        bf16x8 av = *(const bf16x8*)&Vts[(t * 16 + l15) * 32 + ((lq ^ vsw) * 8)];
        acc[t] = __builtin_amdgcn_mfma_f32_16x16x32_bf16(av, bp, acc[t], 0, 0, 0);
      }
    }
  }

#pragma unroll
  for (int rr = 0; rr < 4; ++rr) {
    rs[rr] += __shfl_xor(rs[rr], 1, 64);
    rs[rr] += __shfl_xor(rs[rr], 2, 64);
    rs[rr] += __shfl_xor(rs[rr], 4, 64);
    rs[rr] += __shfl_xor(rs[rr], 8, 64);
  }
  if (l15 == 0) {
#pragma unroll
    for (int rr = 0; rr < 4; ++rr) rsb[w][lq * 4 + rr] = rs[rr];
  }
  asm volatile("s_waitcnt lgkmcnt(0)" ::: "memory");
  __builtin_amdgcn_wave_barrier();
  const float inv = 1.0f / rsb[w][l15];

  const size_t ob = ((size_t)(b * S_ + qw + l15) * NH_ + h) * HD_;
#pragma unroll
  for (int t = 0; t < 16; ++t) {
    ushort4 o;
    o.x = f2bf(acc[t][0] * inv);
    o.y = f2bf(acc[t][1] * inv);
    o.z = f2bf(acc[t][2] * inv);
    o.w = f2bf(acc[t][3] * inv);
    *(ushort4*)&AOb[ob + t * 16 + lq * 4] = o;
  }
}

// ---------------------------------------------------------------------------
extern "C" void kernel_launch(void* const* d_in, const int* in_sizes, int n_in,
                              void* d_out, int out_size, void* d_ws, size_t ws_size,
                              hipStream_t stream) {
  const float* X   = (const float*)d_in[0];
  const int*   pos = (const int*)d_in[2];
  const float* Wq  = (const float*)d_in[3];   // [2304, 2048]
  const float* Wk  = (const float*)d_in[4];   // [2304, 1024]
  const float* Wv  = (const float*)d_in[5];   // [2304, 1024]
  const float* Wo  = (const float*)d_in[6];   // [2048, 2304]
  float* out = (float*)d_out;

  const int M  = B_ * S_;        // 4096
  const int NQ = NH_ * HD_;      // 2048
  const int NK = NKV_ * HD_;     // 1024

  char* w = (char*)d_ws;
  ushort_t* QKV16 = (ushort_t*)w;  w += (size_t)M * QKVW * 2;          // 32 MB
  ushort_t* Xb    = (ushort_t*)w;  w += (size_t)M * H_ * 2;            // 18 MB
  ushort_t* Wqkvt = (ushort_t*)w;  w += (size_t)QKVW * H_ * 2;         // 18 MB
  ushort_t* Wot   = (ushort_t*)w;  w += (size_t)H_ * NQ * 2;           // 9.4 MB
  ushort_t* Vt16  = (ushort_t*)w;  w += (size_t)B_ * NKV_ * S_ * HD_ * 2;  // 8 MB
  ushort_t* AOb   = (ushort_t*)w;  w += (size_t)M * NQ * 2;            // 16 MB

  // opt-in to 128 KiB dynamic LDS for the pipelined GEMM (host-side, capture-safe)
  static bool g_init = false, g_8ph_ok = false;
  if (!g_init) {
    hipError_t e1 = hipFuncSetAttribute(
        reinterpret_cast<const void*>(&gemm_8ph<true>),
        hipFuncAttributeMaxDynamicSharedMemorySize, 131072);
    hipError_t e2 = hipFuncSetAttribute(
        reinterpret_cast<const void*>(&gemm_8ph<false>),
        hipFuncAttributeMaxDynamicSharedMemorySize, 131072);
    g_8ph_ok = (e1 == hipSuccess && e2 == hipSuccess);
    g_init = true;
  }

  dim3 blk(256);

  cast_bf16<<<(M * H_) / 1024, blk, 0, stream>>>(X, Xb);
  // concatenated transposed QKV weights: rows [0,2048)=Wq^T, [2048,3072)=Wk^T, [3072,4096)=Wv^T
  transpose_cast<<<dim3(NQ / 32, H_ / 32), blk, 0, stream>>>(Wq, Wqkvt, H_, NQ);
  transpose_cast<<<dim3(NK / 32, H_ / 32), blk, 0, stream>>>(Wk, Wqkvt + (size_t)2048 * H_, H_, NK);
  transpose_cast<<<dim3(NK / 32, H_ / 32), blk, 0, stream>>>(Wv, Wqkvt + (size_t)3072 * H_, H_, NK);
  transpose_cast<<<dim3(H_ / 32, NQ / 32), blk, 0, stream>>>(Wo, Wot, NQ, H_);

  // fused QKV projection, bf16 out (K=2304: 36 K-tiles; grid 16x16=256 blocks)
  if (g_8ph_ok) {
    gemm_8ph<true><<<dim3(QKVW / 256, M / 256), dim3(512), 131072, stream>>>(
        Xb, Wqkvt, QKV16, M, QKVW, H_);
  } else {
    gemm_bt<true><<<dim3(QKVW / 128, M / 128), blk, 0, stream>>>(Xb, Wqkvt, QKV16, M, QKVW, H_);
  }

  rope_inplace<<<dim3(M, 6), blk, 0, stream>>>(QKV16, pos);
  v_prep<<<dim3(S_ / 32, HD_ / 32, B_ * NKV_), blk, 0, stream>>>(QKV16, Vt16);

  // attention: head-pair per block, 512 threads
  attn_mfma<<<dim3(S_ / 64, NKV_, B_), dim3(512), 0, stream>>>(QKV16, Vt16, AOb);

  // output projection, fp32 out (K=2048: 32 K-tiles; grid 9x16=144 blocks)
  if (g_8ph_ok) {
    gemm_8ph<false><<<dim3(H_ / 256, M / 256), dim3(512), 131072, stream>>>(
        AOb, Wot, out, M, H_, NQ);
  } else {
    gemm_bt<false><<<dim3(H_ / 128, M / 128), blk, 0, stream>>>(AOb, Wot, out, M, H_, NQ);
  }
}

// Round 4
// 349.116 us; speedup vs baseline: 1.8035x; 1.8035x over previous
//
#include <hip/hip_runtime.h>
#include <cmath>

#define B_   2
#define S_   2048
#define H_   2304
#define NH_  8
#define HD_  256
#define NKV_ 4
#define WIN_ 512
#define QKVW 4096   // fused QKV output row width (8+4+4 heads * 256)

typedef unsigned short ushort_t;
typedef __attribute__((ext_vector_type(8))) short bf16x8;     // 8 bf16 = 4 VGPRs
typedef __attribute__((ext_vector_type(4))) float floatx4;

// round-to-nearest-even fp32 -> bf16
__device__ __forceinline__ unsigned short f2bf(float f) {
  unsigned u = __builtin_bit_cast(unsigned, f);
  u += 0x7fff + ((u >> 16) & 1);
  return (unsigned short)(u >> 16);
}
__device__ __forceinline__ float bf2f(ushort_t v) {
  unsigned u = (unsigned)v << 16;
  return __builtin_bit_cast(float, u);
}

// async global->LDS, 16 B per lane. LDS dest = wave-uniform base + lane*16.
__device__ __forceinline__ void gl2lds16(const void* g, void* l) {
  __builtin_amdgcn_global_load_lds(
      (const __attribute__((address_space(1))) unsigned int*)g,
      (__attribute__((address_space(3))) unsigned int*)l, 16, 0, 0);
}

// ---------------------------------------------------------------------------
// Elementwise fp32 -> bf16 cast (4 elems/thread).
// ---------------------------------------------------------------------------
__global__ void cast_bf16(const float* __restrict__ in, ushort_t* __restrict__ out) {
  const int i = blockIdx.x * 256 + threadIdx.x;
  float4 v = ((const float4*)in)[i];
  ushort4 o;
  o.x = f2bf(v.x); o.y = f2bf(v.y); o.z = f2bf(v.z); o.w = f2bf(v.w);
  ((ushort4*)out)[i] = o;
}

// ---------------------------------------------------------------------------
// W[K,N] fp32 -> Wt[N,K] bf16 (32x32 LDS tiles, 256 threads).
// ---------------------------------------------------------------------------
__global__ void transpose_cast(const float* __restrict__ W, ushort_t* __restrict__ Wt,
                               int K, int N) {
  __shared__ float t[32][33];
  const int lx = threadIdx.x & 31, ly = threadIdx.x >> 5;   // ly 0..7
  const int n0 = blockIdx.x * 32, k0 = blockIdx.y * 32;
#pragma unroll
  for (int i = 0; i < 4; ++i)
    t[ly + i * 8][lx] = W[(long long)(k0 + ly + i * 8) * N + n0 + lx];
  __syncthreads();
#pragma unroll
  for (int i = 0; i < 4; ++i)
    Wt[(long long)(n0 + ly + i * 8) * K + k0 + lx] = f2bf(t[lx][ly + i * 8]);
}

// ===========================================================================
// 256x256-tile bf16 MFMA GEMM, v4: kk-split 8-sub-phase pipeline.
//   C[M,N] = A[M,K] @ Bt[N,K]^T
// 512 threads = 8 waves (2M x 4N), per-wave 128x64 (acc[8][4]), BK=64,
// 128 KiB dynamic LDS double buffer, global_load_lds width=16 with
// chunk^(row&7) swizzle via pre-swizzled GLOBAL source (linear LDS dest).
//
// Each sub-phase: {reads for NEXT sub-phase (2-4 ds_read_b128) | 0-1
// staging slot | 8 MFMAs on operands read LAST sub-phase}. Fragment sets
// a0,a1 (16 VGPR each), b0,b1 (8 each) = 48 frag VGPR total (v3's 96
// spilled). Gray-code item order (qm,qn,kk):
//   S1(0,0,0) S2(0,1,0) S3(1,1,0) S4(1,0,0) S5(1,0,1) S6(1,1,1)
//   S7(0,1,1) S8(0,0,1)
// Reads (X=this tile's buf, Y=next):  S1 b1<-X.B(1,0)  S2 a1<-X.A(1,0)
//   S3 a0<-X.A(1,1)  S4 b1<-X.B(0,1)  S5 b0<-X.B(1,1)  S6 a1<-X.A(0,1)
//   S7 a0<-Y.A(0,0)  S8 b0<-Y.B(0,0)
// Stages: S1 A1(t+1)->Y; S6 B0(t+2)->X; S7 B1(t+2)->X; S8 A0(t+2)->X.
// Each staged region's reads were CONSUMED by an MFMA before a barrier
// that precedes the stage issue (no in-flight-read WAR window):
//   B0 death S5-mfma |BAR| stage S6;  B1 death S6 |BAR| S7;
//   A0 death S7 |BAR| S8;  A1 death prior tile.
// Barriers: ends of S5, S6, S7 (3/K-tile). vmcnt ledger (per wave, 2
// loads/slot): at S6 outstanding = {B0,B1,A0,A1}(t+1) + B0(t+2) = 10;
// VM(2) drains tile t+1 exactly (Y complete for S7/S8 reads). Tail:
// VM(0) when no t+2 stages. Auto-waitcnt provides counted lgkm waits;
// sched_barrier(0) pins sub-phase order.
// ===========================================================================
#define RA(dst_, base_, qm_, kk_) do { \
  _Pragma("unroll") for (int i_ = 0; i_ < 4; ++i_) { \
    const int row_ = wm + (qm_) * 64 + i_ * 16 + l15; \
    dst_[i_] = *(const bf16x8*)&(base_)[row_ * 64 + ((((kk_) * 4 + lq) ^ (l15 & 7)) * 8)]; \
  } \
} while (0)

#define RB(dst_, base_, qn_, kk_) do { \
  _Pragma("unroll") for (int j_ = 0; j_ < 2; ++j_) { \
    const int row_ = wn + (qn_) * 32 + j_ * 16 + l15; \
    dst_[j_] = *(const bf16x8*)&(base_)[row_ * 64 + ((((kk_) * 4 + lq) ^ (l15 & 7)) * 8)]; \
  } \
} while (0)

#define MFMA8(qm_, qn_, as_, bs_) do { \
  __builtin_amdgcn_s_setprio(1); \
  _Pragma("unroll") for (int i_ = 0; i_ < 4; ++i_) \
  _Pragma("unroll") for (int j_ = 0; j_ < 2; ++j_) \
    acc[(qm_) * 4 + i_][(qn_) * 2 + j_] = __builtin_amdgcn_mfma_f32_16x16x32_bf16( \
        as_[i_], bs_[j_], acc[(qm_) * 4 + i_][(qn_) * 2 + j_], 0, 0, 0); \
  __builtin_amdgcn_s_setprio(0); \
} while (0)

// stage one 128-row x 64-col half-tile (16 KB): 2 x global_load_lds per lane.
#define STAGE_A(dst_, gsrc_, t_, qm_) do { \
  _Pragma("unroll") for (int jj_ = 0; jj_ < 2; ++jj_) { \
    const int g_ = w * 2 + jj_; \
    const int tr0_ = ((g_ >> 3) * 128) + (qm_) * 64 + (g_ & 7) * 8; \
    gl2lds16(gsrc_ + (size_t)tr0_ * K + (size_t)(t_) * 64 + laneOff, dst_ + tr0_ * 64); \
  } \
} while (0)

#define STAGE_B(dst_, gsrc_, t_, qn_) do { \
  _Pragma("unroll") for (int jj_ = 0; jj_ < 2; ++jj_) { \
    const int g_ = w * 2 + jj_; \
    const int tr0_ = ((g_ >> 2) * 64) + (qn_) * 32 + (g_ & 3) * 8; \
    gl2lds16(gsrc_ + (size_t)tr0_ * K + (size_t)(t_) * 64 + laneOff, dst_ + tr0_ * 64); \
  } \
} while (0)

#define SB0()  __builtin_amdgcn_sched_barrier(0)
#define BAR()  asm volatile("s_barrier" ::: "memory")
#define VM(n_) asm volatile("s_waitcnt vmcnt(" #n_ ")" ::: "memory")

// one K-tile = 8 sub-phases; XA_/XB_ = this tile's LDS, YA_/YB_ = next's.
#define KTILE(XA_, XB_, YA_, YB_, t_) do { \
  /* S1: mfma(0,0)k0 a0,b0 */ \
  RB(b1, XB_, 1, 0); \
  if ((t_) + 1 < NT) STAGE_A(YA_, Ab, (t_) + 1, 1); \
  MFMA8(0, 0, a0, b0); SB0(); \
  /* S2: mfma(0,1)k0 a0,b1 */ \
  RA(a1, XA_, 1, 0); \
  MFMA8(0, 1, a0, b1); SB0(); \
  /* S3: mfma(1,1)k0 a1,b1 */ \
  RA(a0, XA_, 1, 1); \
  MFMA8(1, 1, a1, b1); SB0(); \
  /* S4: mfma(1,0)k0 a1,b0 */ \
  RB(b1, XB_, 0, 1); \
  MFMA8(1, 0, a1, b0); SB0(); \
  /* S5: mfma(1,0)k1 a0,b1 */ \
  RB(b0, XB_, 1, 1); \
  MFMA8(1, 0, a0, b1); SB0(); BAR(); \
  /* S6: mfma(1,1)k1 a0,b0 | stage B0(t+2) | vmcnt */ \
  RA(a1, XA_, 0, 1); \
  if ((t_) + 2 < NT) STAGE_B(XB_, Bb, (t_) + 2, 0); \
  MFMA8(1, 1, a0, b0); \
  if ((t_) + 2 < NT) { VM(2); } else if ((t_) + 1 < NT) { VM(0); } \
  SB0(); BAR(); \
  /* S7: mfma(0,1)k1 a1,b0 | reads Y.A(0,0) | stage B1(t+2) */ \
  if ((t_) + 1 < NT) RA(a0, YA_, 0, 0); \
  if ((t_) + 2 < NT) STAGE_B(XB_, Bb, (t_) + 2, 1); \
  MFMA8(0, 1, a1, b0); SB0(); BAR(); \
  /* S8: mfma(0,0)k1 a1,b1 | reads Y.B(0,0) | stage A0(t+2) */ \
  if ((t_) + 1 < NT) RB(b0, YB_, 0, 0); \
  if ((t_) + 2 < NT) STAGE_A(XA_, Ab, (t_) + 2, 0); \
  MFMA8(0, 0, a1, b1); SB0(); \
} while (0)

template <bool OUT_BF16>
__launch_bounds__(512)
__global__ void gemm_8ph(const ushort_t* __restrict__ A,   // [M,K] bf16
                         const ushort_t* __restrict__ Bt,  // [N,K] bf16
                         void* __restrict__ Cv, int M, int N, int K) {
  extern __shared__ __attribute__((aligned(128))) ushort_t smem[];
  const int tid = threadIdx.x, lane = tid & 63, w = tid >> 6;   // w 0..7
  const int wm = (w >> 2) * 128, wn = (w & 3) * 64;
  const int l15 = lane & 15, lq = lane >> 4;

  // T1: XCD-aware swizzle of the linear block id (grid %8 == 0)
  const int nwg  = gridDim.x * gridDim.y;
  const int orig = blockIdx.y * gridDim.x + blockIdx.x;
  const int cpx  = nwg >> 3;
  const int swz  = (orig & 7) * cpx + (orig >> 3);
  const int bx   = swz % gridDim.x, by = swz / gridDim.x;
  const int bm = by * 256, bn = bx * 256;
  const int NT = K >> 6;   // 36 (QKV) — even

  const ushort_t* Ab = A + (size_t)bm * K;
  const ushort_t* Bb = Bt + (size_t)bn * K;
  // per-lane source offset: row += lane>>3, chunk = (lane&7)^(lane>>3) (swizzle)
  const size_t laneOff = (size_t)(lane >> 3) * K + (size_t)(((lane & 7) ^ (lane >> 3)) * 8);

  ushort_t* Ae = smem;              // even-tile A (256x64)
  ushort_t* Ao = smem + 16384;      // odd-tile  A
  ushort_t* Be = smem + 32768;      // even-tile B
  ushort_t* Bo = smem + 49152;      // odd-tile  B

  floatx4 acc[8][4] = {};
  bf16x8 a0[4], a1[4], b0[2], b1[2];

  // ---- prologue: tile0 fully (8 loads), then tile1 {B0,B1,A0} (6 loads)
  STAGE_A(Ae, Ab, 0, 0);
  STAGE_B(Be, Bb, 0, 0);
  STAGE_B(Be, Bb, 0, 1);
  STAGE_A(Ae, Ab, 0, 1);
  if (NT > 1) {
    STAGE_B(Bo, Bb, 1, 0);
    STAGE_B(Bo, Bb, 1, 1);
    STAGE_A(Ao, Ab, 1, 0);
    VM(6);                        // drain tile0; tile1's 6 loads in flight
  } else {
    VM(0);
  }
  BAR();
  RA(a0, Ae, 0, 0);               // A(0,0) of tile0
  RB(b0, Be, 0, 0);               // B(0,0) of tile0

  for (int t = 0; t < NT; t += 2) {
    KTILE(Ae, Be, Ao, Bo, t);
    KTILE(Ao, Bo, Ae, Be, t + 1);
  }

  // ---- epilogue: C write (C/D layout: row = lq*4+rr, col = l15 per 16x16 frag)
  const int r0 = lq * 4;
#pragma unroll
  for (int mf = 0; mf < 8; ++mf)
#pragma unroll
    for (int nf = 0; nf < 4; ++nf) {
      const long long base = (long long)(bm + wm + mf * 16 + r0) * N + bn + wn + nf * 16 + l15;
      if (OUT_BF16) {
        ushort_t* Cp = (ushort_t*)Cv + base;
#pragma unroll
        for (int rr = 0; rr < 4; ++rr) Cp[(long long)rr * N] = f2bf(acc[mf][nf][rr]);
      } else {
        float* Cp = (float*)Cv + base;
#pragma unroll
        for (int rr = 0; rr < 4; ++rr) Cp[(long long)rr * N] = acc[mf][nf][rr];
      }
    }
}

#undef RA
#undef RB
#undef MFMA8
#undef STAGE_A
#undef STAGE_B
#undef SB0
#undef BAR
#undef VM
#undef KTILE

// ---------------------------------------------------------------------------
// 128x128 GEMM (register-double-buffered) — used for the output projection
// (576 blocks saturate all CUs; the 256-tile grid is only 144 blocks) and
// as fallback if the dynamic-LDS attribute is unavailable.
// ---------------------------------------------------------------------------
template <bool OUT_BF16>
__launch_bounds__(256)
__global__ void gemm_bt(const ushort_t* __restrict__ A,   // [M,K] bf16
                        const ushort_t* __restrict__ Bt,  // [N,K] bf16
                        void* __restrict__ Cv, int M, int N, int K) {
  __shared__ ushort_t As[128 * 64];
  __shared__ ushort_t Bs[128 * 64];
  const int tid = threadIdx.x, lane = tid & 63, wid = tid >> 6;
  const int bm = blockIdx.y * 128, bn = blockIdx.x * 128;
  const int wm = (wid >> 1) * 64, wn = (wid & 1) * 64;

  floatx4 acc[4][4] = {};

  const int r  = tid >> 1;
  const int cp = (tid & 1) * 4;
  const int wkey = r & 7;
  const ushort_t* Ap = A  + (long long)(bm + r) * K + cp * 8;
  const ushort_t* Bp = Bt + (long long)(bn + r) * K + cp * 8;
  ushort_t* Aw = &As[r * 64];
  ushort_t* Bw = &Bs[r * 64];

  const int l15 = lane & 15, lq = lane >> 4;
  const int rkey = l15 & 7;

  bf16x8 ar[4], br[4];
#pragma unroll
  for (int i = 0; i < 4; ++i) {
    ar[i] = *(const bf16x8*)(Ap + i * 8);
    br[i] = *(const bf16x8*)(Bp + i * 8);
  }

  for (int k0 = 0; k0 < K; k0 += 64) {
    __syncthreads();
#pragma unroll
    for (int i = 0; i < 4; ++i) {
      *(bf16x8*)&Aw[((cp + i) ^ wkey) * 8] = ar[i];
      *(bf16x8*)&Bw[((cp + i) ^ wkey) * 8] = br[i];
    }
    __syncthreads();

    if (k0 + 64 < K) {
      const int kn = k0 + 64;
#pragma unroll
      for (int i = 0; i < 4; ++i) {
        ar[i] = *(const bf16x8*)(Ap + kn + i * 8);
        br[i] = *(const bf16x8*)(Bp + kn + i * 8);
      }
    }

#pragma unroll
    for (int kk = 0; kk < 2; ++kk) {
      bf16x8 af[4], bfr[4];
#pragma unroll
      for (int i = 0; i < 4; ++i) {
        af[i]  = *(const bf16x8*)&As[(wm + i * 16 + l15) * 64 + ((kk * 4 + lq) ^ rkey) * 8];
        bfr[i] = *(const bf16x8*)&Bs[(wn + i * 16 + l15) * 64 + ((kk * 4 + lq) ^ rkey) * 8];
      }
#pragma unroll
      for (int i = 0; i < 4; ++i)
#pragma unroll
        for (int j = 0; j < 4; ++j)
          acc[i][j] = __builtin_amdgcn_mfma_f32_16x16x32_bf16(af[i], bfr[j], acc[i][j], 0, 0, 0);
    }
  }

  const int r0 = lq * 4, c0 = l15;
#pragma unroll
  for (int i = 0; i < 4; ++i)
#pragma unroll
    for (int j = 0; j < 4; ++j) {
      const long long base = (long long)(bm + wm + i * 16 + r0) * N + bn + wn + j * 16 + c0;
      if (OUT_BF16) {
        ushort_t* Cp = (ushort_t*)Cv + base;
#pragma unroll
        for (int rr = 0; rr < 4; ++rr) Cp[(long long)rr * N] = f2bf(acc[i][j][rr]);
      } else {
        float* Cp = (float*)Cv + base;
#pragma unroll
        for (int rr = 0; rr < 4; ++rr) Cp[(long long)rr * N] = acc[i][j][rr];
      }
    }
}

// ---------------------------------------------------------------------------
// In-place RoPE on QKV16 [B*S][4096] bf16 (Q cols 0..2047, K cols 2048..3071).
// Also folds the 1/16 attention scale into Q. V region untouched.
// ---------------------------------------------------------------------------
__global__ void rope_inplace(ushort_t* __restrict__ QKV16, const int* __restrict__ pos) {
  const int bs  = blockIdx.x;
  const int gid = blockIdx.y * 256 + threadIdx.x;
  const int head = gid >> 7;          // 0..11
  const int d    = gid & 127;
  const float pp   = (float)pos[bs];
  const float invf = __expf(-(float)d * (9.210340371976184f / 128.0f));
  const float ang  = pp * invf;
  float sn, cc;
  __sincosf(ang, &sn, &cc);
  ushort_t* base = QKV16 + (size_t)bs * QKVW + head * HD_;
  const float x1 = bf2f(base[d]);
  const float x2 = bf2f(base[d + 128]);
  float o1 = x1 * cc - x2 * sn;
  float o2 = x2 * cc + x1 * sn;
  if (head < NH_) { o1 *= 0.0625f; o2 *= 0.0625f; }   // fold 1/sqrt(256) into Q
  base[d]       = f2bf(o1);
  base[d + 128] = f2bf(o2);
}

// ---------------------------------------------------------------------------
// V transpose: QKV16 V region -> Vt16 [B][NKV][256][S] bf16.
// ---------------------------------------------------------------------------
__global__ void v_prep(const ushort_t* __restrict__ QKV16, ushort_t* __restrict__ Vt16) {
  __shared__ ushort_t tile[32][33];
  const int k0 = blockIdx.x * 32, d0 = blockIdx.y * 32;
  const int b = blockIdx.z >> 2, hk = blockIdx.z & 3;
  const int lx = threadIdx.x & 31, ly = threadIdx.x >> 5;
#pragma unroll
  for (int i = 0; i < 4; ++i)
    tile[ly + 8 * i][lx] =
        QKV16[(size_t)(b * S_ + k0 + ly + 8 * i) * QKVW + 3072 + hk * HD_ + d0 + lx];
  __syncthreads();
#pragma unroll
  for (int i = 0; i < 4; ++i)
    Vt16[((size_t)(b * NKV_ + hk) * HD_ + d0 + ly + 8 * i) * S_ + k0 + lx] =
        tile[lx][ly + 8 * i];
}

// ---------------------------------------------------------------------------
// MFMA flash attention, head-PAIR per block (both heads share hk's K/V).
// 512 threads = 8 waves: waves 0-3 -> head 2*hp, waves 4-7 -> head 2*hp+1.
// ---------------------------------------------------------------------------
__launch_bounds__(512)
__global__ void attn_mfma(const ushort_t* __restrict__ QKV16,  // [B*S][4096]
                          const ushort_t* __restrict__ Vt16,   // [B][NKV][256][S]
                          ushort_t* __restrict__ AOb) {        // [B][S][NH][256]
  __shared__ ushort_t Ks[32 * 256];    // [key][dim], chunk-swizzled
  __shared__ ushort_t Vts[256 * 32];   // [dim][key], chunk-swizzled
  __shared__ ushort_t Ps[8][16 * 32];  // per-wave P [q][key], chunk-swizzled
  __shared__ float rsb[8][16];

  const int lane = threadIdx.x & 63, w = threadIdx.x >> 6;   // w 0..7
  const int l15 = lane & 15, lq = lane >> 4;
  const int qb = blockIdx.x * 64;
  const int hp = blockIdx.y, b = blockIdx.z;                 // hp = hk
  const int h  = hp * 2 + (w >> 2);
  const int hw = w & 3;                                      // wave-in-head

  const ushort_t* Qh = QKV16 + (size_t)b * S_ * QKVW + h * HD_;
  const ushort_t* Kh = QKV16 + (size_t)b * S_ * QKVW + 2048 + hp * HD_;
  const ushort_t* Vh = Vt16 + ((size_t)(b * NKV_ + hp) * HD_) * S_;

  const int qw = qb + hw * 16;   // wave's first query

  bf16x8 afq[8];
  {
    const ushort_t* qr = Qh + (size_t)(qw + l15) * QKVW + lq * 8;
#pragma unroll
    for (int kd = 0; kd < 8; ++kd) afq[kd] = *(const bf16x8*)(qr + kd * 32);
  }

  floatx4 acc[16] = {};
  float rs[4] = {0.f, 0.f, 0.f, 0.f};

  int kb0 = qb - (WIN_ - 1);
  if (kb0 < 0) kb0 = 0;
  kb0 &= ~31;

  const int ksp = lane & 31, ksr = lane >> 5;
  const int vsp = lane & 3,  vsr = lane >> 2;

  for (int kb = kb0; kb < qb + 64; kb += 32) {
    __syncthreads();
#pragma unroll
    for (int i = 0; i < 2; ++i) {
      const int kl = w * 4 + 2 * i + ksr;
      gl2lds16(Kh + (size_t)(kb + kl) * QKVW + (ksp ^ (kl & 31)) * 8,
               &Ks[(w * 4 + 2 * i) * 256]);
    }
#pragma unroll
    for (int i = 0; i < 2; ++i) {
      const int dl = w * 32 + 16 * i + vsr;
      gl2lds16(Vh + (size_t)dl * S_ + kb + (vsp ^ ((dl >> 1) & 3)) * 8,
               &Vts[(w * 32 + 16 * i) * 32]);
    }
    __syncthreads();

    if (kb <= qw + 15 && kb + 31 >= qw - (WIN_ - 1)) {
      ushort_t* Pw = Ps[w];
#pragma unroll
      for (int kt = 0; kt < 2; ++kt) {
        floatx4 sacc = {};
        const int keyl = kt * 16 + l15;
        const int krow = keyl * 256;
        const int ksw = keyl & 31;
#pragma unroll
        for (int kd = 0; kd < 8; ++kd) {
          bf16x8 bk = *(const bf16x8*)&Ks[krow + ((kd * 4 + lq) ^ ksw) * 8];
          sacc = __builtin_amdgcn_mfma_f32_16x16x32_bf16(afq[kd], bk, sacc, 0, 0, 0);
        }
        const int keyg = kb + keyl;
#pragma unroll
        for (int rr = 0; rr < 4; ++rr) {
          const int qg = qw + lq * 4 + rr;
          const float t = __expf(sacc[rr] * 0.04f);
          const float L = 50.f - __fdividef(100.f, t + 1.f);
          float p = __expf(L);
          p = (keyg <= qg && keyg >= qg - (WIN_ - 1)) ? p : 0.f;
          rs[rr] += p;
          const int ql = lq * 4 + rr;
          const int ch = kt * 2 + (l15 >> 3);
          Pw[ql * 32 + ((ch ^ ((ql >> 1) & 3)) * 8) + (l15 & 7)] = f2bf(p);
        }
      }
      asm volatile("s_waitcnt lgkmcnt(0)" ::: "memory");

      const bf16x8 bp = *(const bf16x8*)&Pw[l15 * 32 + ((lq ^ ((l15 >> 1) & 3)) * 8)];
      const int vsw = (l15 >> 1) & 3;
#pragma unroll
      for (int t = 0; t < 16; ++t) {
        bf16x8 av = *(const bf16x8*)&Vts[(t * 16 + l15) * 32 + ((lq ^ vsw) * 8)];
        acc[t] = __builtin_amdgcn_mfma_f32_16x16x32_bf16(av, bp, acc[t], 0, 0, 0);
      }
    }
  }

#pragma unroll
  for (int rr = 0; rr < 4; ++rr) {
    rs[rr] += __shfl_xor(rs[rr], 1, 64);
    rs[rr] += __shfl_xor(rs[rr], 2, 64);
    rs[rr] += __shfl_xor(rs[rr], 4, 64);
    rs[rr] += __shfl_xor(rs[rr], 8, 64);
  }
  if (l15 == 0) {
#pragma unroll
    for (int rr = 0; rr < 4; ++rr) rsb[w][lq * 4 + rr] = rs[rr];
  }
  asm volatile("s_waitcnt lgkmcnt(0)" ::: "memory");
  __builtin_amdgcn_wave_barrier();
  const float inv = 1.0f / rsb[w][l15];

  const size_t ob = ((size_t)(b * S_ + qw + l15) * NH_ + h) * HD_;
#pragma unroll
  for (int t = 0; t < 16; ++t) {
    ushort4 o;
    o.x = f2bf(acc[t][0] * inv);
    o.y = f2bf(acc[t][1] * inv);
    o.z = f2bf(acc[t][2] * inv);
    o.w = f2bf(acc[t][3] * inv);
    *(ushort4*)&AOb[ob + t * 16 + lq * 4] = o;
  }
}

// ---------------------------------------------------------------------------
extern "C" void kernel_launch(void* const* d_in, const int* in_sizes, int n_in,
                              void* d_out, int out_size, void* d_ws, size_t ws_size,
                              hipStream_t stream) {
  const float* X   = (const float*)d_in[0];
  const int*   pos = (const int*)d_in[2];
  const float* Wq  = (const float*)d_in[3];   // [2304, 2048]
  const float* Wk  = (const float*)d_in[4];   // [2304, 1024]
  const float* Wv  = (const float*)d_in[5];   // [2304, 1024]
  const float* Wo  = (const float*)d_in[6];   // [2048, 2304]
  float* out = (float*)d_out;

  const int M  = B_ * S_;        // 4096
  const int NQ = NH_ * HD_;      // 2048
  const int NK = NKV_ * HD_;     // 1024

  char* w = (char*)d_ws;
  ushort_t* QKV16 = (ushort_t*)w;  w += (size_t)M * QKVW * 2;          // 32 MB
  ushort_t* Xb    = (ushort_t*)w;  w += (size_t)M * H_ * 2;            // 18 MB
  ushort_t* Wqkvt = (ushort_t*)w;  w += (size_t)QKVW * H_ * 2;         // 18 MB
  ushort_t* Wot   = (ushort_t*)w;  w += (size_t)H_ * NQ * 2;           // 9.4 MB
  ushort_t* Vt16  = (ushort_t*)w;  w += (size_t)B_ * NKV_ * S_ * HD_ * 2;  // 8 MB
  ushort_t* AOb   = (ushort_t*)w;  w += (size_t)M * NQ * 2;            // 16 MB

  // opt-in to 128 KiB dynamic LDS for the pipelined GEMM (host-side, capture-safe)
  static bool g_init = false, g_8ph_ok = false;
  if (!g_init) {
    hipError_t e1 = hipFuncSetAttribute(
        reinterpret_cast<const void*>(&gemm_8ph<true>),
        hipFuncAttributeMaxDynamicSharedMemorySize, 131072);
    g_8ph_ok = (e1 == hipSuccess);
    g_init = true;
  }

  dim3 blk(256);

  cast_bf16<<<(M * H_) / 1024, blk, 0, stream>>>(X, Xb);
  // concatenated transposed QKV weights: rows [0,2048)=Wq^T, [2048,3072)=Wk^T, [3072,4096)=Wv^T
  transpose_cast<<<dim3(NQ / 32, H_ / 32), blk, 0, stream>>>(Wq, Wqkvt, H_, NQ);
  transpose_cast<<<dim3(NK / 32, H_ / 32), blk, 0, stream>>>(Wk, Wqkvt + (size_t)2048 * H_, H_, NK);
  transpose_cast<<<dim3(NK / 32, H_ / 32), blk, 0, stream>>>(Wv, Wqkvt + (size_t)3072 * H_, H_, NK);
  transpose_cast<<<dim3(H_ / 32, NQ / 32), blk, 0, stream>>>(Wo, Wot, NQ, H_);

  // fused QKV projection, bf16 out (K=2304: 36 K-tiles; grid 16x16=256 blocks)
  if (g_8ph_ok) {
    gemm_8ph<true><<<dim3(QKVW / 256, M / 256), dim3(512), 131072, stream>>>(
        Xb, Wqkvt, QKV16, M, QKVW, H_);
  } else {
    gemm_bt<true><<<dim3(QKVW / 128, M / 128), blk, 0, stream>>>(Xb, Wqkvt, QKV16, M, QKVW, H_);
  }

  rope_inplace<<<dim3(M, 6), blk, 0, stream>>>(QKV16, pos);
  v_prep<<<dim3(S_ / 32, HD_ / 32, B_ * NKV_), blk, 0, stream>>>(QKV16, Vt16);

  // attention: head-pair per block, 512 threads
  attn_mfma<<<dim3(S_ / 64, NKV_, B_), dim3(512), 0, stream>>>(QKV16, Vt16, AOb);

  // output projection, fp32 out: 128^2 tiles -> 576 blocks (saturates 256 CUs;
  // the 256-tile grid is only 144 blocks = 44% idle machine)
  gemm_bt<false><<<dim3(H_ / 128, M / 128), blk, 0, stream>>>(AOb, Wot, out, M, H_, NQ);
}